// Round 1
// baseline (69.804 us; speedup 1.0000x reference)
//
#include <hip/hip_runtime.h>
#include <hip/hip_bf16.h>

// out[b,0,i,j] = j even ? -min_{h,w}( sqrt(h^2+(i-w)^2) + fm[b,0,h,w] )
//                       : sqrt(255^2 + max(i,255-i)^2)
// F = 256, B = 8. One block per (b,i); thread t = column w.

#define FSZ 256

__global__ __launch_bounds__(256) void dt2_kernel(const float* __restrict__ fm,
                                                  float* __restrict__ out,
                                                  int B) {
    const int bi = blockIdx.x;          // 0 .. B*FSZ-1
    const int b  = bi >> 8;             // / FSZ
    const int i  = bi & (FSZ - 1);
    const int t  = threadIdx.x;         // w

    const int   d  = i - t;
    const float d2 = (float)(d * d);

    const float* __restrict__ fmb = fm + (size_t)b * FSZ * FSZ + t;

    // two independent accumulators for ILP
    float m0 = 1e30f, m1 = 1e30f;
#pragma unroll 8
    for (int h = 0; h < FSZ; h += 2) {
        float v0 = sqrtf((float)(h * h) + d2)             + fmb[h * FSZ];
        float v1 = sqrtf((float)((h + 1) * (h + 1)) + d2) + fmb[(h + 1) * FSZ];
        m0 = fminf(m0, v0);
        m1 = fminf(m1, v1);
    }
    float m = fminf(m0, m1);

    // wave64 butterfly reduce
#pragma unroll
    for (int off = 1; off < 64; off <<= 1)
        m = fminf(m, __shfl_xor(m, off, 64));

    // cross-wave reduce (4 waves)
    __shared__ float s[4];
    const int wid = t >> 6;
    if ((t & 63) == 0) s[wid] = m;
    __syncthreads();
    const float mv = fminf(fminf(s[0], s[1]), fminf(s[2], s[3]));

    const float me = -mv;
    const float mi = fmaxf((float)i, (float)(FSZ - 1 - i));
    const float mo = sqrtf((float)((FSZ - 1) * (FSZ - 1)) + mi * mi);

    // out row (b,0,i,:) : even j -> me, odd j -> mo
    out[(size_t)bi * FSZ + t] = (t & 1) ? mo : me;
}

extern "C" void kernel_launch(void* const* d_in, const int* in_sizes, int n_in,
                              void* d_out, int out_size, void* d_ws, size_t ws_size,
                              hipStream_t stream) {
    const float* fm = (const float*)d_in[0];
    float* out = (float*)d_out;
    const int B = in_sizes[0] / (FSZ * FSZ);   // = 8
    dt2_kernel<<<B * FSZ, 256, 0, stream>>>(fm, out, B);
}

// Round 2
// 25.475 us; speedup vs baseline: 2.7401x; 2.7401x over previous
//
#include <hip/hip_runtime.h>
#include <hip/hip_bf16.h>

// out[b,0,i,j] = j even ? -min_{h,w}( sqrt(h^2+(i-w)^2) + fm[b,0,h,w] )
//                       : sqrt(255^2 + max(i,255-i)^2)
// F = 256, B = 8. One block per (b, i-pair); thread t = column w.
// KI=2 output rows per block share the fm loads and the h^2 converts.
// __builtin_amdgcn_sqrtf -> bare v_sqrt_f32 (libm sqrtf emits a ~20cy
// correctly-rounded fixup sequence; threshold is 7.2 so 1-ulp approx is fine).

#define FSZ 256
#define KI 2

__global__ __launch_bounds__(256) void dt2_kernel(const float* __restrict__ fm,
                                                  float* __restrict__ out,
                                                  int B) {
    const int blk = blockIdx.x;                 // 0 .. B*(FSZ/KI)-1
    const int b   = blk / (FSZ / KI);
    const int i0  = (blk % (FSZ / KI)) * KI;
    const int t   = threadIdx.x;                // w

    float d2[KI];
#pragma unroll
    for (int k = 0; k < KI; ++k) {
        const int d = (i0 + k) - t;
        d2[k] = (float)(d * d);                 // loop-invariant per thread
    }

    const float* __restrict__ fmb = fm + (size_t)b * FSZ * FSZ + t;

    float m[KI];
#pragma unroll
    for (int k = 0; k < KI; ++k) m[k] = 1e30f;

#pragma unroll 8
    for (int h = 0; h < FSZ; h += 2) {
        const float f0  = fmb[h * FSZ];
        const float f1  = fmb[(h + 1) * FSZ];
        const float h2a = (float)(h * h);             // wave-uniform
        const float h2b = (float)((h + 1) * (h + 1));
#pragma unroll
        for (int k = 0; k < KI; ++k) {
            const float v0 = __builtin_amdgcn_sqrtf(h2a + d2[k]) + f0;
            const float v1 = __builtin_amdgcn_sqrtf(h2b + d2[k]) + f1;
            m[k] = fminf(fminf(m[k], v0), v1);        // v_min3_f32
        }
    }

    // wave64 butterfly reduce per k
#pragma unroll
    for (int off = 1; off < 64; off <<= 1) {
#pragma unroll
        for (int k = 0; k < KI; ++k)
            m[k] = fminf(m[k], __shfl_xor(m[k], off, 64));
    }

    // cross-wave reduce (4 waves)
    __shared__ float s[4][KI];
    const int wid = t >> 6;
    if ((t & 63) == 0) {
#pragma unroll
        for (int k = 0; k < KI; ++k) s[wid][k] = m[k];
    }
    __syncthreads();

#pragma unroll
    for (int k = 0; k < KI; ++k) {
        const float mv = fminf(fminf(s[0][k], s[1][k]), fminf(s[2][k], s[3][k]));
        const float me = -mv;
        const int   i  = i0 + k;
        const float mi = fmaxf((float)i, (float)(FSZ - 1 - i));
        const float mo = __builtin_amdgcn_sqrtf((float)((FSZ - 1) * (FSZ - 1)) + mi * mi);
        out[((size_t)b * FSZ + i) * FSZ + t] = (t & 1) ? mo : me;
    }
}

extern "C" void kernel_launch(void* const* d_in, const int* in_sizes, int n_in,
                              void* d_out, int out_size, void* d_ws, size_t ws_size,
                              hipStream_t stream) {
    const float* fm = (const float*)d_in[0];
    float* out = (float*)d_out;
    const int B = in_sizes[0] / (FSZ * FSZ);   // = 8
    dt2_kernel<<<B * (FSZ / KI), 256, 0, stream>>>(fm, out, B);
}